// Round 10
// baseline (183.949 us; speedup 1.0000x reference)
//
#include <hip/hip_runtime.h>
#include <math.h>

// Problem constants
#define R_   1152
#define C_   10
#define D_   16
#define I_   8
#define B_   256
#define N_   160      // C_*D_ (n = c*16+d)
#define K_   9216     // R_*I_ (k = r*8+i)
#define KS_  32       // K-split across blocks
#define KC_  288      // K_/KS_ per block (9 chunks of 32 k = 4 r-rows)

// workspace layout (float offsets); ~14 MB
#define OFF_WSUM  0                      //    92,160  Wsum[r][c][i]
#define OFF_TT    92160                  // 2,949,120  tT[c][b][r]
#define OFF_BIJ   (OFF_TT + 2949120)     //   184,320  bij[r][n]
#define OFF_E     (OFF_BIJ + 184320)     //   184,320  E[r][n] = exp(bij)
#define OFF_S0    (OFF_E + 184320)       //    40,960  s iter0
#define OFF_S1    (OFF_S0 + 40960)       //    40,960  s iter1
#define OFF_S2    (OFF_S1 + 40960)       //    40,960  s iter2
#define OFF_NSA   (OFF_S2 + 40960)       //       160  nsumA
#define OFF_NSB   (OFF_NSA + 160)        //       160  nsumB
// S0..NSB contiguous: 3*40960 + 320 = 123200 floats -> zeroed by prep

// ---------------------------------------------------------------------------
// prep: blocks [0,360): Wsum[r,c,i] = sum_d W[r,c,d,i]
//       blocks [360,480): zero s0/s1/s2/nsumA/nsumB (123200 floats, grid-stride f4)
__global__ void prep_kernel(const float* __restrict__ W, float* __restrict__ Wsum,
                            float* __restrict__ zbase) {
    int bid = blockIdx.x, tid = threadIdx.x;
    if (bid >= 360) {
        float4 z = {0.0f, 0.0f, 0.0f, 0.0f};
        for (int q = (bid - 360) * 256 + tid; q < 30800; q += 120 * 256)
            ((float4*)zbase)[q] = z;
        return;
    }
    int idx = bid * 256 + tid;                         // 92160 exact
    int r = idx / (C_ * I_);
    int rem = idx % (C_ * I_);
    int c = rem / I_;
    int i = rem % I_;
    const float* p = W + (size_t)r * (C_ * D_ * I_) + c * (D_ * I_) + i;
    float s = 0.0f;
#pragma unroll
    for (int d = 0; d < D_; ++d) s += p[d * I_];
    Wsum[idx] = s;
}

// ---------------------------------------------------------------------------
// GEMM: s[b][n] (atomic+)= sum_{k slice} u[b][k] * W[r][n][i] * (HASE ? E[r][n] : 1)
// Barrier-free pipelined K-loop (R8-proven). 20 KB LDS total (K-loop quarters
// reused as two-phase epilogue reduce arena) -> 4 blocks/CU (vs 2 at 40 KB).
// When !HASE, extra blocks [512,872) run the t-pass (tT from Wsum+u).
template <int HASE>
__launch_bounds__(256, 4)
__global__ void gemm_kernel(const float* __restrict__ u, const float* __restrict__ W,
                            const float* __restrict__ E, float* __restrict__ s,
                            const float* __restrict__ Wsum, float* __restrict__ tT) {
    int tid = threadIdx.x;
    if (!HASE && blockIdx.x >= 512) {                  // fused t-pass
        for (int idx = (blockIdx.x - 512) * 256 + tid; idx < B_ * R_; idx += 360 * 256) {
            int r = idx % R_;
            int b = idx / R_;
            const float4* up = (const float4*)(u + (size_t)idx * I_);
            float4 a0 = up[0], a1 = up[1];
            const float* wp = Wsum + (size_t)r * (C_ * I_);
            float outv[C_];
#pragma unroll
            for (int c = 0; c < C_; ++c) {
                const float4* w4 = (const float4*)(wp + c * I_);
                float4 w0 = w4[0], w1 = w4[1];
                outv[c] = a0.x * w0.x + a0.y * w0.y + a0.z * w0.z + a0.w * w0.w
                        + a1.x * w1.x + a1.y * w1.y + a1.z * w1.z + a1.w * w1.w;
            }
#pragma unroll
            for (int c = 0; c < C_; ++c)
                tT[((size_t)c * B_ + b) * R_ + r] = outv[c];   // coalesced in r
        }
        return;
    }

    __shared__ float smem[5120];    // 20 KB: 4 wave-quarters / epilogue red arena
    int wave = tid >> 6, lane = tid & 63;
    int ng = lane & 15, bg = lane >> 4;
    int ks = blockIdx.x & 31, bt = blockIdx.x >> 5;    // 32 ks x 16 bt
    int b0 = bt * 16;
    int n0 = ng * 10;

    float acc[4][10];
#pragma unroll
    for (int m = 0; m < 4; ++m)
#pragma unroll
        for (int j = 0; j < 10; ++j) acc[m][j] = 0.0f;

    const float* ur[4];
#pragma unroll
    for (int m = 0; m < 4; ++m) ur[m] = u + (size_t)(b0 + bg * 4 + m) * K_;

    // prefetch chunk 0: idx = it*64+lane in [0,320); n = idx>>1; i-half = (idx&1)*4
    float4 wr[5];
    float  ee[5];
    {
        int r = ks * 36 + wave;
#pragma unroll
        for (int it = 0; it < 5; ++it) {
            int idx = it * 64 + lane;
            wr[it] = *(const float4*)(W + (size_t)r * 1280 + idx * 4);
            if (HASE) ee[it] = E[r * N_ + (idx >> 1)];
        }
    }

    int ldsbase = wave * 1280;
    for (int c = 0; c < 9; ++c) {
        // stage chunk c into private wave quarter (transpose i into rows)
#pragma unroll
        for (int it = 0; it < 5; ++it) {
            int idx = it * 64 + lane;
            int n = idx >> 1, ih = (idx & 1) * 4;
            float e = HASE ? ee[it] : 1.0f;
            float* q = &smem[ldsbase + ih * 160 + n];
            q[0]   = wr[it].x * e;
            q[160] = wr[it].y * e;
            q[320] = wr[it].z * e;
            q[480] = wr[it].w * e;
        }
        // prefetch chunk c+1 (clamped refetch keeps pipeline uniform)
        {
            int cn = (c + 1 < 9) ? (c + 1) : 0;
            int r = ks * 36 + cn * 4 + wave;
#pragma unroll
            for (int it = 0; it < 5; ++it) {
                int idx = it * 64 + lane;
                wr[it] = *(const float4*)(W + (size_t)r * 1280 + idx * 4);
                if (HASE) ee[it] = E[r * N_ + (idx >> 1)];
            }
        }
        // compute chunk c
#pragma unroll
        for (int g = 0; g < 2; ++g) {
            int kabs = ks * KC_ + c * 32 + wave * 8 + g * 4;
            float ua[4][4];
#pragma unroll
            for (int m = 0; m < 4; ++m) {
                float4 tmp = *(const float4*)(ur[m] + kabs);
                ua[m][0] = tmp.x; ua[m][1] = tmp.y; ua[m][2] = tmp.z; ua[m][3] = tmp.w;
            }
#pragma unroll
            for (int t4 = 0; t4 < 4; ++t4) {
                const float* wrow = &smem[ldsbase + (g * 4 + t4) * 160 + n0];
                float w[10];
#pragma unroll
                for (int j = 0; j < 10; j += 2) {
                    float2 ww = *(const float2*)(wrow + j);
                    w[j] = ww.x; w[j + 1] = ww.y;
                }
#pragma unroll
                for (int m = 0; m < 4; ++m)
#pragma unroll
                    for (int j = 0; j < 10; ++j)
                        acc[m][j] = fmaf(ua[m][t4], w[j], acc[m][j]);
            }
        }
    }

    // two-phase epilogue reduce in the 20 KB arena, then atomic into s
    __syncthreads();
    if (wave >= 2) {
#pragma unroll
        for (int m = 0; m < 4; ++m)
#pragma unroll
            for (int j = 0; j < 10; ++j)
                smem[(wave - 2) * 2560 + (bg * 4 + m) * N_ + n0 + j] = acc[m][j];
    }
    __syncthreads();
    if (wave < 2) {
#pragma unroll
        for (int m = 0; m < 4; ++m)
#pragma unroll
            for (int j = 0; j < 10; ++j) {
                int o = wave * 2560 + (bg * 4 + m) * N_ + n0 + j;
                smem[o] += acc[m][j];
            }
    }
    __syncthreads();
    float* sp = s + (size_t)b0 * N_;
    for (int f = tid; f < 2560; f += 256)
        atomicAdd(&sp[f], smem[f] + smem[2560 + f]);
}

// ---------------------------------------------------------------------------
// bupd: per block (c, r0-tile of 64):
//   vs[b][d] = squash( s[b][c*16+d] * scale  OR  / nsum_in[c*16+d] )
//   bij[r][n] (+)= (1/B) sum_b vs[b][d] * tT[c][b][r]
//   E[r][n] = exp(bij); nsum_out[n] += sum_r E   (max-free softmax)
__launch_bounds__(256)
__global__ void bupd_kernel(const float* __restrict__ s, const float* __restrict__ nsum_in,
                            float scale, const float* __restrict__ tT,
                            float* __restrict__ bij, float* __restrict__ E,
                            float* __restrict__ nsum_out, int accumulate) {
    __shared__ float vs[B_ * 16];     // [b][d] 16 KB
    __shared__ float red[16 * 256];   // [d][tid] 16 KB
    int tid = threadIdx.x;
    int c = blockIdx.x % 10;
    int r0 = (blockIdx.x / 10) * 64;
    int rsub = tid & 63, bs = tid >> 6;

    // v-slice from the already-reduced s (16 KB read)
    for (int q = tid; q < 1024; q += 256) {
        int b = q >> 2, d4 = q & 3;
        float4 a = *(const float4*)(s + (size_t)b * N_ + c * 16 + d4 * 4);
        if (nsum_in) {
            float4 nv = *(const float4*)(nsum_in + c * 16 + d4 * 4);
            a.x /= nv.x; a.y /= nv.y; a.z /= nv.z; a.w /= nv.w;
        } else {
            a.x *= scale; a.y *= scale; a.z *= scale; a.w *= scale;
        }
        float4 o;
        {
            float t = a.x; float sq = t * t;
            o.x = sq / (1.0f + sq) * t / (sqrtf(sq) + 1e-5f);
            t = a.y; sq = t * t;
            o.y = sq / (1.0f + sq) * t / (sqrtf(sq) + 1e-5f);
            t = a.z; sq = t * t;
            o.z = sq / (1.0f + sq) * t / (sqrtf(sq) + 1e-5f);
            t = a.w; sq = t * t;
            o.w = sq / (1.0f + sq) * t / (sqrtf(sq) + 1e-5f);
        }
        ((float4*)vs)[q] = o;
    }
    __syncthreads();

    float acc[16];
#pragma unroll
    for (int d = 0; d < 16; ++d) acc[d] = 0.0f;

    const float* tp = tT + ((size_t)c * B_ + bs * 64) * R_ + r0 + rsub;
    for (int bb = 0; bb < 64; ++bb) {
        float tv = tp[(size_t)bb * R_];                     // coalesced across wave
        const float4* vrow = (const float4*)(vs + (bs * 64 + bb) * 16); // uniform bcast
        float4 v0 = vrow[0], v1 = vrow[1], v2 = vrow[2], v3 = vrow[3];
        acc[0]  = fmaf(tv, v0.x, acc[0]);  acc[1]  = fmaf(tv, v0.y, acc[1]);
        acc[2]  = fmaf(tv, v0.z, acc[2]);  acc[3]  = fmaf(tv, v0.w, acc[3]);
        acc[4]  = fmaf(tv, v1.x, acc[4]);  acc[5]  = fmaf(tv, v1.y, acc[5]);
        acc[6]  = fmaf(tv, v1.z, acc[6]);  acc[7]  = fmaf(tv, v1.w, acc[7]);
        acc[8]  = fmaf(tv, v2.x, acc[8]);  acc[9]  = fmaf(tv, v2.y, acc[9]);
        acc[10] = fmaf(tv, v2.z, acc[10]); acc[11] = fmaf(tv, v2.w, acc[11]);
        acc[12] = fmaf(tv, v3.x, acc[12]); acc[13] = fmaf(tv, v3.y, acc[13]);
        acc[14] = fmaf(tv, v3.z, acc[14]); acc[15] = fmaf(tv, v3.w, acc[15]);
    }
#pragma unroll
    for (int d = 0; d < 16; ++d) red[d * 256 + tid] = acc[d];
    __syncthreads();

#pragma unroll
    for (int j = 0; j < 4; ++j) {
        int q = tid + 256 * j;
        int rr = q & 63, d = q >> 6;                   // d uniform per wave
        const float* rp = red + d * 256 + rr;
        float v = (rp[0] + rp[64] + rp[128] + rp[192]) * (1.0f / B_);
        int o = (r0 + rr) * N_ + c * 16 + d;
        if (accumulate) v += bij[o];
        bij[o] = v;
        float ex = __expf(v);                          // max-free: |bij| = O(1)
        E[o] = ex;
#pragma unroll
        for (int off = 32; off > 0; off >>= 1) ex += __shfl_down(ex, off, 64);
        if (rr == 0) atomicAdd(&nsum_out[c * 16 + d], ex);
    }
}

// ---------------------------------------------------------------------------
// out = squash(s2 / nsum)
__global__ void rs_kernel(const float* __restrict__ s, const float* __restrict__ nsum,
                          float* __restrict__ out) {
    int g = blockIdx.x * 256 + threadIdx.x;            // 160 blocks -> 40960 exact
    float t = s[g] / nsum[g % N_];
    float sq = t * t;
    out[g] = sq / (1.0f + sq) * t / (sqrtf(sq) + 1e-5f);
}

// ---------------------------------------------------------------------------
extern "C" void kernel_launch(void* const* d_in, const int* in_sizes, int n_in,
                              void* d_out, int out_size, void* d_ws, size_t ws_size,
                              hipStream_t stream) {
    (void)in_sizes; (void)n_in; (void)out_size; (void)ws_size;
    const float* u = (const float*)d_in[0];
    const float* W = (const float*)d_in[1];
    float* out = (float*)d_out;
    float* ws = (float*)d_ws;

    float* Wsum  = ws + OFF_WSUM;
    float* tT    = ws + OFF_TT;
    float* bij   = ws + OFF_BIJ;
    float* E     = ws + OFF_E;
    float* s0    = ws + OFF_S0;
    float* s1    = ws + OFF_S1;
    float* s2    = ws + OFF_S2;
    float* nsumA = ws + OFF_NSA;
    float* nsumB = ws + OFF_NSB;

    // 7 dispatches
    prep_kernel<<<480, 256, 0, stream>>>(W, Wsum, s0 /* zero region base */);

    gemm_kernel<0><<<872, 256, 0, stream>>>(u, W, nullptr, s0, Wsum, tT);
    bupd_kernel<<<180, 256, 0, stream>>>(s0, nullptr, 1.0f / 1152.0f, tT,
                                         bij, E, nsumA, 0);

    gemm_kernel<1><<<512, 256, 0, stream>>>(u, W, E, s1, nullptr, nullptr);
    bupd_kernel<<<180, 256, 0, stream>>>(s1, nsumA, 0.0f, tT,
                                         bij, E, nsumB, 1);

    gemm_kernel<1><<<512, 256, 0, stream>>>(u, W, E, s2, nullptr, nullptr);
    rs_kernel<<<160, 256, 0, stream>>>(s2, nsumB, out);
}